// Round 11
// baseline (143.380 us; speedup 1.0000x reference)
//
#include <hip/hip_runtime.h>

#define TN 2048
#define TD 1024
#define TC 8192
#define MARGINV 0.3f
#define EPSV 0.1f

#define BT 64
#define KC 64
#define NTILE (TN / BT)                  // 32
#define NPAIR (NTILE * (NTILE + 1) / 2)  // 528 triplet tiles
#define NBLK (NPAIR + TN)                // 2576 = 16 * 161
#define GRP 161                          // per group: 33 triplet + 128 CE
#define TPG 33

// ---- ws layout ----
static constexpr size_t OFF_FH = 0;                      // N*D ushort (f16 bits, 4MB)
static constexpr size_t OFF_SQ = (size_t)4 << 20;        // N float  |f_r|^2
static constexpr size_t OFF_AP = OFF_SQ + TN * 4;        // N uint   (float bits, hardest-pos)
static constexpr size_t OFF_AN = OFF_AP + TN * 4;        // N uint   (float bits, hardest-neg)
static constexpr size_t OFF_CE = OFF_AN + TN * 4;        // N float  per-row CE loss
static constexpr size_t OFF_CD = OFF_CE + TN * 4;        // N float  per-row center dist^2

typedef __attribute__((ext_vector_type(8))) _Float16 f16x8;
typedef __attribute__((ext_vector_type(4))) float f32x4;

__device__ __forceinline__ unsigned short f2h(float x) {
    _Float16 h = (_Float16)x;                  // v_cvt_f16_f32 (RTN)
    unsigned short b;
    __builtin_memcpy(&b, &h, 2);
    return b;
}

// async global->LDS, 16B per lane; LDS dest linear in lane order (m104/m108)
__device__ __forceinline__ void gld16(const void* g, void* l) {
    __builtin_amdgcn_global_load_lds(
        (const __attribute__((address_space(1))) void*)g,
        (__attribute__((address_space(3))) void*)l, 16, 0, 0);
}

// ------------------------------------------------------------------
// prep: F -> f16, sq norms, per-row center dist, ap/an init
// ------------------------------------------------------------------
__global__ __launch_bounds__(256)
void prep_k(const float* __restrict__ F, const float* __restrict__ centers,
            const int* __restrict__ labels, unsigned short* __restrict__ fh,
            float* __restrict__ sqn, unsigned* __restrict__ ap,
            unsigned* __restrict__ an, float* __restrict__ cdist) {
    const int r = blockIdx.x, t = threadIdx.x;
    const int lane = t & 63, wid = t >> 6;
    const int lbl = labels[r];

    float4 f = ((const float4*)(F + (size_t)r * TD))[t];
    float4 c = ((const float4*)(centers + (size_t)lbl * TD))[t];

    float sff = f.x * f.x + f.y * f.y + f.z * f.z + f.w * f.w;
    float sfc = f.x * c.x + f.y * c.y + f.z * c.z + f.w * c.w;
    float scc = c.x * c.x + c.y * c.y + c.z * c.z + c.w * c.w;

    ushort4 h;
    h.x = f2h(f.x); h.y = f2h(f.y); h.z = f2h(f.z); h.w = f2h(f.w);
    ((ushort4*)(fh + (size_t)r * TD))[t] = h;

    __shared__ float red[3][4];
    #pragma unroll
    for (int m = 32; m; m >>= 1) {
        sff += __shfl_down(sff, m, 64);
        sfc += __shfl_down(sfc, m, 64);
        scc += __shfl_down(scc, m, 64);
    }
    if (lane == 0) { red[0][wid] = sff; red[1][wid] = sfc; red[2][wid] = scc; }
    __syncthreads();
    if (t == 0) {
        sff = red[0][0] + red[0][1] + red[0][2] + red[0][3];
        sfc = red[1][0] + red[1][1] + red[1][2] + red[1][3];
        scc = red[2][0] + red[2][1] + red[2][2] + red[2][3];
        sqn[r] = sff;
        ap[r] = 0u;            // max of nonneg floats in uint-bit domain
        an[r] = 0x7f800000u;   // +inf
        float d = sff + scc - 2.f * sfc;
        cdist[r] = fminf(fmaxf(d, 1e-12f), 1e12f);
    }
}

// ------------------------------------------------------------------
// FAT kernel, role-INTERLEAVED so triplet (MFMA-bound) and CE
// (HBM-bound) blocks are co-resident from dispatch t=0:
// groups of 161 blocks = 33 triplet + 128 CE via Bresenham unranking
// (33<161 -> floor((k+1)*33/161) - floor(k*33/161) in {0,1}; bijective).
// Triplet: symmetric upper-triangle 64x64 Gram tiles (f16 MFMA),
// updating hardest pos/neg for BOTH rows and cols (idempotent atomics).
// CE: one row per block, online softmax, per-row result (no hot atomics).
// ------------------------------------------------------------------
__global__ __launch_bounds__(256, 2)
void fat_k(const unsigned short* __restrict__ fh, const float* __restrict__ logits,
           const int* __restrict__ labels, const float* __restrict__ sqn,
           unsigned* __restrict__ ap, unsigned* __restrict__ an,
           float* __restrict__ celoss) {
    __shared__ unsigned short lA[BT * KC], lB[BT * KC];   // 16KB (triplet)
    __shared__ float wm[4], wsum[4], wtot[4];             // (CE)

    const int t = threadIdx.x, lane = t & 63, wid = t >> 6;

    const int g = blockIdx.x / GRP, k = blockIdx.x % GRP;
    const int fk = (k * TPG) / GRP;
    const bool isTrip = ((k + 1) * TPG) / GRP > fk;

    if (isTrip) {
        // ---------------- triplet path ----------------
        // unrank triplet id -> (tb_i, tb_j), 0 <= tb_i <= tb_j < NTILE
        int b = g * TPG + fk;
        int tb_i = 0;
        {
            int off = 0;
            #pragma unroll 1
            while (b >= off + (NTILE - tb_i)) { off += NTILE - tb_i; ++tb_i; }
            b -= off;
        }
        const int tb_j = tb_i + b;

        const int wrow = (wid >> 1) * 32, wcol = (wid & 1) * 32;
        const int rowBase = tb_i * BT, colBase = tb_j * BT;

        f32x4 acc[2][2];
        #pragma unroll
        for (int i = 0; i < 2; ++i)
            #pragma unroll
            for (int j = 0; j < 2; ++j) acc[i][j] = (f32x4){0.f, 0.f, 0.f, 0.f};

        for (int kc = 0; kc < TD / KC; ++kc) {
            const int k0 = kc * KC;
            __syncthreads();                       // LDS reuse fence
            // Stage 64x64-f16 tiles; LDS dest linear (global_load_lds
            // requirement), XOR swizzle applied on the SOURCE granule and
            // inverted identically on fragment reads (rule #21 / m173).
            #pragma unroll
            for (int ii = 0; ii < 2; ++ii) {
                int idx = t + ii * 256;            // 0..511 16B-granules
                int row = idx >> 3, gs = idx & 7;
                int gsrc = gs ^ (row & 7);
                gld16(fh + (size_t)(rowBase + row) * TD + k0 + gsrc * 8, &lA[idx * 8]);
                gld16(fh + (size_t)(colBase + row) * TD + k0 + gsrc * 8, &lB[idx * 8]);
            }
            __syncthreads();                       // drains vmcnt + barrier

            #pragma unroll
            for (int s = 0; s < 2; ++s) {          // two k=32 steps
                f16x8 ah[2], bh[2];
                #pragma unroll
                for (int ti = 0; ti < 2; ++ti) {
                    int row = wrow + ti * 16 + (lane & 15);
                    int gq = s * 4 + (lane >> 4);
                    int off = row * 128 + ((gq ^ (row & 7)) << 4);
                    ah[ti] = *(const f16x8*)((const char*)lA + off);
                }
                #pragma unroll
                for (int tj = 0; tj < 2; ++tj) {
                    int col = wcol + tj * 16 + (lane & 15);
                    int gq = s * 4 + (lane >> 4);
                    int off = col * 128 + ((gq ^ (col & 7)) << 4);
                    bh[tj] = *(const f16x8*)((const char*)lB + off);
                }
                #pragma unroll
                for (int ti = 0; ti < 2; ++ti)
                    #pragma unroll
                    for (int tj = 0; tj < 2; ++tj)
                        acc[ti][tj] = __builtin_amdgcn_mfma_f32_16x16x32_f16(
                            ah[ti], bh[tj], acc[ti][tj], 0, 0, 0);
            }
        }

        // ---- epilogue: dist + hardest pos/neg, row-side AND col-side ----
        float sqc[2]; int lc[2];
        #pragma unroll
        for (int tj = 0; tj < 2; ++tj) {
            int cg = colBase + wcol + tj * 16 + (lane & 15);
            sqc[tj] = sqn[cg]; lc[tj] = labels[cg];
        }
        float maxp[8], minn[8], cmax[2], cmin[2];
        #pragma unroll
        for (int i = 0; i < 8; ++i) { maxp[i] = 0.f; minn[i] = 1e30f; }
        #pragma unroll
        for (int i = 0; i < 2; ++i) { cmax[i] = 0.f; cmin[i] = 1e30f; }

        #pragma unroll
        for (int ti = 0; ti < 2; ++ti) {
            #pragma unroll
            for (int reg = 0; reg < 4; ++reg) {
                int rg = rowBase + wrow + ti * 16 + (lane >> 4) * 4 + reg;
                float sqr = sqn[rg];
                int lr = labels[rg];
                #pragma unroll
                for (int tj = 0; tj < 2; ++tj) {
                    float d2 = sqr + sqc[tj] - 2.f * acc[ti][tj][reg];
                    float d = sqrtf(fmaxf(d2, 1e-12f));
                    int id = ti * 4 + reg;
                    if (lr == lc[tj]) { maxp[id] = fmaxf(maxp[id], d); cmax[tj] = fmaxf(cmax[tj], d); }
                    else              { minn[id] = fminf(minn[id], d); cmin[tj] = fminf(cmin[tj], d); }
                }
            }
        }

        // row-side: reduce over the 16 col-lanes (lane bits 0..3)
        #pragma unroll
        for (int i = 0; i < 8; ++i) {
            #pragma unroll
            for (int m = 1; m < 16; m <<= 1) {
                maxp[i] = fmaxf(maxp[i], __shfl_xor(maxp[i], m, 64));
                minn[i] = fminf(minn[i], __shfl_xor(minn[i], m, 64));
            }
        }
        if ((lane & 15) == 0) {
            #pragma unroll
            for (int ti = 0; ti < 2; ++ti)
                #pragma unroll
                for (int reg = 0; reg < 4; ++reg) {
                    int rg = rowBase + wrow + ti * 16 + (lane >> 4) * 4 + reg;
                    int i = ti * 4 + reg;
                    atomicMax(&ap[rg], __float_as_uint(maxp[i]));
                    atomicMin(&an[rg], __float_as_uint(minn[i]));
                }
        }

        // col-side: reduce over the 4 row-groups (lane bits 4..5)
        #pragma unroll
        for (int tj = 0; tj < 2; ++tj) {
            #pragma unroll
            for (int m = 16; m < 64; m <<= 1) {
                cmax[tj] = fmaxf(cmax[tj], __shfl_xor(cmax[tj], m, 64));
                cmin[tj] = fminf(cmin[tj], __shfl_xor(cmin[tj], m, 64));
            }
        }
        if ((lane >> 4) == 0) {
            #pragma unroll
            for (int tj = 0; tj < 2; ++tj) {
                int cg = colBase + wcol + tj * 16 + (lane & 15);
                atomicMax(&ap[cg], __float_as_uint(cmax[tj]));
                atomicMin(&an[cg], __float_as_uint(cmin[tj]));
            }
        }
    } else {
        // ---------------- CE path (one row per block) ----------------
        const int r = g * (GRP - TPG) + (k - fk);
        const float4* lrow = (const float4*)(logits + (size_t)r * TC);
        float m = -1e30f, s = 0.f, tot = 0.f;
        #pragma unroll
        for (int i = 0; i < TC / 4 / 256; ++i) {   // 8 iters of float4
            float4 v = lrow[t + i * 256];
            tot += (v.x + v.y) + (v.z + v.w);
            float mx = fmaxf(fmaxf(v.x, v.y), fmaxf(v.z, v.w));
            if (mx > m) { s *= __expf(m - mx); m = mx; }
            s += __expf(v.x - m) + __expf(v.y - m) + __expf(v.z - m) + __expf(v.w - m);
        }
        // wave-level online-softmax combine (no barriers)
        #pragma unroll
        for (int o = 32; o; o >>= 1) {
            float m2 = __shfl_down(m, o, 64), s2 = __shfl_down(s, o, 64);
            float t2 = __shfl_down(tot, o, 64);
            float mN = fmaxf(m, m2);
            s = s * __expf(m - mN) + s2 * __expf(m2 - mN);
            m = mN; tot += t2;
        }
        if (lane == 0) { wm[wid] = m; wsum[wid] = s; wtot[wid] = tot; }
        __syncthreads();
        if (t == 0) {
            m = wm[0]; s = wsum[0]; tot = wtot[0];
            #pragma unroll
            for (int w = 1; w < 4; ++w) {
                float mN = fmaxf(m, wm[w]);
                s = s * __expf(m - mN) + wsum[w] * __expf(wm[w] - mN);
                m = mN; tot += wtot[w];
            }
            float lse = m + logf(s);
            float xl = logits[(size_t)r * TC + labels[r]];
            celoss[r] = (1.f - EPSV) * (lse - xl) + EPSV * lse - (EPSV / TC) * tot;
        }
    }
}

// ------------------------------------------------------------------
// final combine (no hot atomics anywhere: all per-row arrays)
// ------------------------------------------------------------------
__global__ __launch_bounds__(256)
void final_k(const unsigned* __restrict__ ap, const unsigned* __restrict__ an,
             const float* __restrict__ celoss, const float* __restrict__ cdist,
             float* __restrict__ out) {
    const int t = threadIdx.x;
    float sm = 0.f, sc = 0.f, sd = 0.f;
    #pragma unroll
    for (int i = 0; i < TN / 256; ++i) {
        int r = t + i * 256;
        sm += fmaxf(__uint_as_float(ap[r]) - __uint_as_float(an[r]) + MARGINV, 0.f);
        sc += celoss[r];
        sd += cdist[r];
    }
    __shared__ float red[3][4];
    #pragma unroll
    for (int m = 32; m; m >>= 1) {
        sm += __shfl_down(sm, m, 64);
        sc += __shfl_down(sc, m, 64);
        sd += __shfl_down(sd, m, 64);
    }
    if ((t & 63) == 0) { red[0][t >> 6] = sm; red[1][t >> 6] = sc; red[2][t >> 6] = sd; }
    __syncthreads();
    if (t == 0) {
        sm = red[0][0] + red[0][1] + red[0][2] + red[0][3];
        sc = red[1][0] + red[1][1] + red[1][2] + red[1][3];
        sd = red[2][0] + red[2][1] + red[2][2] + red[2][3];
        out[0] = (sm + sc + 5e-4f * sd) * (1.0f / TN);
    }
}

extern "C" void kernel_launch(void* const* d_in, const int* in_sizes, int n_in,
                              void* d_out, int out_size, void* d_ws, size_t ws_size,
                              hipStream_t stream) {
    const float* F       = (const float*)d_in[0];
    const float* logits  = (const float*)d_in[1];
    const float* centers = (const float*)d_in[2];
    const int*   labels  = (const int*)d_in[3];
    float* out = (float*)d_out;

    char* ws = (char*)d_ws;
    unsigned short* fh = (unsigned short*)(ws + OFF_FH);
    float*    sqn    = (float*)(ws + OFF_SQ);
    unsigned* ap     = (unsigned*)(ws + OFF_AP);
    unsigned* an     = (unsigned*)(ws + OFF_AN);
    float*    celoss = (float*)(ws + OFF_CE);
    float*    cdist  = (float*)(ws + OFF_CD);

    prep_k<<<TN, 256, 0, stream>>>(F, centers, labels, fh, sqn, ap, an, cdist);
    fat_k<<<NBLK, 256, 0, stream>>>(fh, logits, labels, sqn, ap, an, celoss);
    final_k<<<1, 256, 0, stream>>>(ap, an, celoss, cdist, out);
}

// Round 13
// 142.700 us; speedup vs baseline: 1.0048x; 1.0048x over previous
//
#include <hip/hip_runtime.h>

#define TN 2048
#define TD 1024
#define TC 8192
#define MARGINV 0.3f
#define EPSV 0.1f

#define BT 64
#define KC 64
#define NTILE (TN / BT)                  // 32
#define NPAIR (NTILE * (NTILE + 1) / 2)  // 528 triplet tiles
#define NBLK (NPAIR + TN)                // 2576 = 16 * 161
#define GRP 161                          // per group: 33 triplet + 128 CE
#define TPG 33

// ---- ws layout ----
static constexpr size_t OFF_FH = 0;                      // N*D ushort (f16 bits, 4MB)
static constexpr size_t OFF_SQ = (size_t)4 << 20;        // N float  |f_r|^2
static constexpr size_t OFF_AP = OFF_SQ + TN * 4;        // N uint   (float bits, hardest-pos)
static constexpr size_t OFF_AN = OFF_AP + TN * 4;        // N uint   (float bits, hardest-neg)
static constexpr size_t OFF_CE = OFF_AN + TN * 4;        // N float  per-row CE loss
static constexpr size_t OFF_CD = OFF_CE + TN * 4;        // N float  per-row center dist^2

typedef __attribute__((ext_vector_type(8))) _Float16 f16x8;
typedef __attribute__((ext_vector_type(4))) float f32x4;

__device__ __forceinline__ unsigned short f2h(float x) {
    _Float16 h = (_Float16)x;                  // v_cvt_f16_f32 (RTN)
    unsigned short b;
    __builtin_memcpy(&b, &h, 2);
    return b;
}

// async global->LDS, 16B per lane; LDS dest linear in lane order (m104/m108)
__device__ __forceinline__ void gld16(const void* g, void* l) {
    __builtin_amdgcn_global_load_lds(
        (const __attribute__((address_space(1))) void*)g,
        (__attribute__((address_space(3))) void*)l, 16, 0, 0);
}

// ------------------------------------------------------------------
// prep: F -> f16, sq norms, per-row center dist, ap/an init
// ------------------------------------------------------------------
__global__ __launch_bounds__(256)
void prep_k(const float* __restrict__ F, const float* __restrict__ centers,
            const int* __restrict__ labels, unsigned short* __restrict__ fh,
            float* __restrict__ sqn, unsigned* __restrict__ ap,
            unsigned* __restrict__ an, float* __restrict__ cdist) {
    const int r = blockIdx.x, t = threadIdx.x;
    const int lane = t & 63, wid = t >> 6;
    const int lbl = labels[r];

    float4 f = ((const float4*)(F + (size_t)r * TD))[t];
    float4 c = ((const float4*)(centers + (size_t)lbl * TD))[t];

    float sff = f.x * f.x + f.y * f.y + f.z * f.z + f.w * f.w;
    float sfc = f.x * c.x + f.y * c.y + f.z * c.z + f.w * c.w;
    float scc = c.x * c.x + c.y * c.y + c.z * c.z + c.w * c.w;

    ushort4 h;
    h.x = f2h(f.x); h.y = f2h(f.y); h.z = f2h(f.z); h.w = f2h(f.w);
    ((ushort4*)(fh + (size_t)r * TD))[t] = h;

    __shared__ float red[3][4];
    #pragma unroll
    for (int m = 32; m; m >>= 1) {
        sff += __shfl_down(sff, m, 64);
        sfc += __shfl_down(sfc, m, 64);
        scc += __shfl_down(scc, m, 64);
    }
    if (lane == 0) { red[0][wid] = sff; red[1][wid] = sfc; red[2][wid] = scc; }
    __syncthreads();
    if (t == 0) {
        sff = red[0][0] + red[0][1] + red[0][2] + red[0][3];
        sfc = red[1][0] + red[1][1] + red[1][2] + red[1][3];
        scc = red[2][0] + red[2][1] + red[2][2] + red[2][3];
        sqn[r] = sff;
        ap[r] = 0u;            // max of nonneg floats in uint-bit domain
        an[r] = 0x7f800000u;   // +inf
        float d = sff + scc - 2.f * sfc;
        cdist[r] = fminf(fmaxf(d, 1e-12f), 1e12f);
    }
}

// ------------------------------------------------------------------
// FAT kernel, role-INTERLEAVED so triplet (MFMA-bound) and CE
// (HBM-bound) blocks are co-resident from dispatch t=0:
// groups of 161 blocks = 33 triplet + 128 CE via Bresenham unranking
// (33<161 -> floor((k+1)*33/161) - floor(k*33/161) in {0,1}; bijective).
// R11 change (pending bench): min-waves 2 -> 4 (VGPR cap 128; hand-count
// ~110) to double blocks/CU 2->4 for better CE latency hiding + overlap.
// ------------------------------------------------------------------
__global__ __launch_bounds__(256, 4)
void fat_k(const unsigned short* __restrict__ fh, const float* __restrict__ logits,
           const int* __restrict__ labels, const float* __restrict__ sqn,
           unsigned* __restrict__ ap, unsigned* __restrict__ an,
           float* __restrict__ celoss) {
    __shared__ unsigned short lA[BT * KC], lB[BT * KC];   // 16KB (triplet)
    __shared__ float wm[4], wsum[4], wtot[4];             // (CE)

    const int t = threadIdx.x, lane = t & 63, wid = t >> 6;

    const int g = blockIdx.x / GRP, k = blockIdx.x % GRP;
    const int fk = (k * TPG) / GRP;
    const bool isTrip = ((k + 1) * TPG) / GRP > fk;

    if (isTrip) {
        // ---------------- triplet path ----------------
        // unrank triplet id -> (tb_i, tb_j), 0 <= tb_i <= tb_j < NTILE
        int b = g * TPG + fk;
        int tb_i = 0;
        {
            int off = 0;
            #pragma unroll 1
            while (b >= off + (NTILE - tb_i)) { off += NTILE - tb_i; ++tb_i; }
            b -= off;
        }
        const int tb_j = tb_i + b;

        const int wrow = (wid >> 1) * 32, wcol = (wid & 1) * 32;
        const int rowBase = tb_i * BT, colBase = tb_j * BT;

        f32x4 acc[2][2];
        #pragma unroll
        for (int i = 0; i < 2; ++i)
            #pragma unroll
            for (int j = 0; j < 2; ++j) acc[i][j] = (f32x4){0.f, 0.f, 0.f, 0.f};

        for (int kc = 0; kc < TD / KC; ++kc) {
            const int k0 = kc * KC;
            __syncthreads();                       // LDS reuse fence
            // Stage 64x64-f16 tiles; LDS dest linear (global_load_lds
            // requirement), XOR swizzle applied on the SOURCE granule and
            // inverted identically on fragment reads (rule #21 / m173).
            #pragma unroll
            for (int ii = 0; ii < 2; ++ii) {
                int idx = t + ii * 256;            // 0..511 16B-granules
                int row = idx >> 3, gs = idx & 7;
                int gsrc = gs ^ (row & 7);
                gld16(fh + (size_t)(rowBase + row) * TD + k0 + gsrc * 8, &lA[idx * 8]);
                gld16(fh + (size_t)(colBase + row) * TD + k0 + gsrc * 8, &lB[idx * 8]);
            }
            __syncthreads();                       // drains vmcnt + barrier

            #pragma unroll
            for (int s = 0; s < 2; ++s) {          // two k=32 steps
                f16x8 ah[2], bh[2];
                #pragma unroll
                for (int ti = 0; ti < 2; ++ti) {
                    int row = wrow + ti * 16 + (lane & 15);
                    int gq = s * 4 + (lane >> 4);
                    int off = row * 128 + ((gq ^ (row & 7)) << 4);
                    ah[ti] = *(const f16x8*)((const char*)lA + off);
                }
                #pragma unroll
                for (int tj = 0; tj < 2; ++tj) {
                    int col = wcol + tj * 16 + (lane & 15);
                    int gq = s * 4 + (lane >> 4);
                    int off = col * 128 + ((gq ^ (col & 7)) << 4);
                    bh[tj] = *(const f16x8*)((const char*)lB + off);
                }
                #pragma unroll
                for (int ti = 0; ti < 2; ++ti)
                    #pragma unroll
                    for (int tj = 0; tj < 2; ++tj)
                        acc[ti][tj] = __builtin_amdgcn_mfma_f32_16x16x32_f16(
                            ah[ti], bh[tj], acc[ti][tj], 0, 0, 0);
            }
        }

        // ---- epilogue: dist + hardest pos/neg, row-side AND col-side ----
        float sqc[2]; int lc[2];
        #pragma unroll
        for (int tj = 0; tj < 2; ++tj) {
            int cg = colBase + wcol + tj * 16 + (lane & 15);
            sqc[tj] = sqn[cg]; lc[tj] = labels[cg];
        }
        float maxp[8], minn[8], cmax[2], cmin[2];
        #pragma unroll
        for (int i = 0; i < 8; ++i) { maxp[i] = 0.f; minn[i] = 1e30f; }
        #pragma unroll
        for (int i = 0; i < 2; ++i) { cmax[i] = 0.f; cmin[i] = 1e30f; }

        #pragma unroll
        for (int ti = 0; ti < 2; ++ti) {
            #pragma unroll
            for (int reg = 0; reg < 4; ++reg) {
                int rg = rowBase + wrow + ti * 16 + (lane >> 4) * 4 + reg;
                float sqr = sqn[rg];
                int lr = labels[rg];
                #pragma unroll
                for (int tj = 0; tj < 2; ++tj) {
                    float d2 = sqr + sqc[tj] - 2.f * acc[ti][tj][reg];
                    float d = sqrtf(fmaxf(d2, 1e-12f));
                    int id = ti * 4 + reg;
                    if (lr == lc[tj]) { maxp[id] = fmaxf(maxp[id], d); cmax[tj] = fmaxf(cmax[tj], d); }
                    else              { minn[id] = fminf(minn[id], d); cmin[tj] = fminf(cmin[tj], d); }
                }
            }
        }

        // row-side: reduce over the 16 col-lanes (lane bits 0..3)
        #pragma unroll
        for (int i = 0; i < 8; ++i) {
            #pragma unroll
            for (int m = 1; m < 16; m <<= 1) {
                maxp[i] = fmaxf(maxp[i], __shfl_xor(maxp[i], m, 64));
                minn[i] = fminf(minn[i], __shfl_xor(minn[i], m, 64));
            }
        }
        if ((lane & 15) == 0) {
            #pragma unroll
            for (int ti = 0; ti < 2; ++ti)
                #pragma unroll
                for (int reg = 0; reg < 4; ++reg) {
                    int rg = rowBase + wrow + ti * 16 + (lane >> 4) * 4 + reg;
                    int i = ti * 4 + reg;
                    atomicMax(&ap[rg], __float_as_uint(maxp[i]));
                    atomicMin(&an[rg], __float_as_uint(minn[i]));
                }
        }

        // col-side: reduce over the 4 row-groups (lane bits 4..5)
        #pragma unroll
        for (int tj = 0; tj < 2; ++tj) {
            #pragma unroll
            for (int m = 16; m < 64; m <<= 1) {
                cmax[tj] = fmaxf(cmax[tj], __shfl_xor(cmax[tj], m, 64));
                cmin[tj] = fminf(cmin[tj], __shfl_xor(cmin[tj], m, 64));
            }
        }
        if ((lane >> 4) == 0) {
            #pragma unroll
            for (int tj = 0; tj < 2; ++tj) {
                int cg = colBase + wcol + tj * 16 + (lane & 15);
                atomicMax(&ap[cg], __float_as_uint(cmax[tj]));
                atomicMin(&an[cg], __float_as_uint(cmin[tj]));
            }
        }
    } else {
        // ---------------- CE path (one row per block) ----------------
        const int r = g * (GRP - TPG) + (k - fk);
        const float4* lrow = (const float4*)(logits + (size_t)r * TC);
        float m = -1e30f, s = 0.f, tot = 0.f;
        #pragma unroll
        for (int i = 0; i < TC / 4 / 256; ++i) {   // 8 iters of float4
            float4 v = lrow[t + i * 256];
            tot += (v.x + v.y) + (v.z + v.w);
            float mx = fmaxf(fmaxf(v.x, v.y), fmaxf(v.z, v.w));
            if (mx > m) { s *= __expf(m - mx); m = mx; }
            s += __expf(v.x - m) + __expf(v.y - m) + __expf(v.z - m) + __expf(v.w - m);
        }
        // wave-level online-softmax combine (no barriers)
        #pragma unroll
        for (int o = 32; o; o >>= 1) {
            float m2 = __shfl_down(m, o, 64), s2 = __shfl_down(s, o, 64);
            float t2 = __shfl_down(tot, o, 64);
            float mN = fmaxf(m, m2);
            s = s * __expf(m - mN) + s2 * __expf(m2 - mN);
            m = mN; tot += t2;
        }
        if (lane == 0) { wm[wid] = m; wsum[wid] = s; wtot[wid] = tot; }
        __syncthreads();
        if (t == 0) {
            m = wm[0]; s = wsum[0]; tot = wtot[0];
            #pragma unroll
            for (int w = 1; w < 4; ++w) {
                float mN = fmaxf(m, wm[w]);
                s = s * __expf(m - mN) + wsum[w] * __expf(wm[w] - mN);
                m = mN; tot += wtot[w];
            }
            float lse = m + logf(s);
            float xl = logits[(size_t)r * TC + labels[r]];
            celoss[r] = (1.f - EPSV) * (lse - xl) + EPSV * lse - (EPSV / TC) * tot;
        }
    }
}

// ------------------------------------------------------------------
// final combine (no hot atomics anywhere: all per-row arrays)
// ------------------------------------------------------------------
__global__ __launch_bounds__(256)
void final_k(const unsigned* __restrict__ ap, const unsigned* __restrict__ an,
             const float* __restrict__ celoss, const float* __restrict__ cdist,
             float* __restrict__ out) {
    const int t = threadIdx.x;
    float sm = 0.f, sc = 0.f, sd = 0.f;
    #pragma unroll
    for (int i = 0; i < TN / 256; ++i) {
        int r = t + i * 256;
        sm += fmaxf(__uint_as_float(ap[r]) - __uint_as_float(an[r]) + MARGINV, 0.f);
        sc += celoss[r];
        sd += cdist[r];
    }
    __shared__ float red[3][4];
    #pragma unroll
    for (int m = 32; m; m >>= 1) {
        sm += __shfl_down(sm, m, 64);
        sc += __shfl_down(sc, m, 64);
        sd += __shfl_down(sd, m, 64);
    }
    if ((t & 63) == 0) { red[0][t >> 6] = sm; red[1][t >> 6] = sc; red[2][t >> 6] = sd; }
    __syncthreads();
    if (t == 0) {
        sm = red[0][0] + red[0][1] + red[0][2] + red[0][3];
        sc = red[1][0] + red[1][1] + red[1][2] + red[1][3];
        sd = red[2][0] + red[2][1] + red[2][2] + red[2][3];
        out[0] = (sm + sc + 5e-4f * sd) * (1.0f / TN);
    }
}

extern "C" void kernel_launch(void* const* d_in, const int* in_sizes, int n_in,
                              void* d_out, int out_size, void* d_ws, size_t ws_size,
                              hipStream_t stream) {
    const float* F       = (const float*)d_in[0];
    const float* logits  = (const float*)d_in[1];
    const float* centers = (const float*)d_in[2];
    const int*   labels  = (const int*)d_in[3];
    float* out = (float*)d_out;

    char* ws = (char*)d_ws;
    unsigned short* fh = (unsigned short*)(ws + OFF_FH);
    float*    sqn    = (float*)(ws + OFF_SQ);
    unsigned* ap     = (unsigned*)(ws + OFF_AP);
    unsigned* an     = (unsigned*)(ws + OFF_AN);
    float*    celoss = (float*)(ws + OFF_CE);
    float*    cdist  = (float*)(ws + OFF_CD);

    prep_k<<<TN, 256, 0, stream>>>(F, centers, labels, fh, sqn, ap, an, cdist);
    fat_k<<<NBLK, 256, 0, stream>>>(fh, logits, labels, sqn, ap, an, celoss);
    final_k<<<1, 256, 0, stream>>>(ap, an, celoss, cdist, out);
}